// Round 4
// baseline (284.419 us; speedup 1.0000x reference)
//
#include <hip/hip_runtime.h>

// Gate3: out[r][c] = g(x1[r][c>>2]) + g(x2[r][c>>1]) + g(x3[r][c]),
// g(x) = sigmoid(x*w + b) * x; out (B,16,1) == flat (B*16,) fp32.
//
// Memory-bound streaming: 224 MiB read + 128 MiB write, roofline ~59 us.
// Decomposition: one thread per QUARTER-row (i = row*4 + q). Every access
// is unit-stride across lanes, 100% utilized:
//   x1: scalar  x1[i]   (4 B/lane)
//   x2: float2  x2[2i]  (8 B/lane)
//   x3: float4  x3[4i]  (16 B/lane)
//   out: float4 out[4i] (16 B/lane)
// 7 gate evals/thread; gates of repeated cols computed once.
// NOTE (round-3 post-mortem): do NOT pass floats through
// __builtin_amdgcn_readfirstlane — it's int(int) and value-converts
// (truncated w,b to 0 -> absmax 4.02 failure). Plain uniform loads
// already land in SGPRs via s_load.

typedef float v2f __attribute__((ext_vector_type(2)));
typedef float v4f __attribute__((ext_vector_type(4)));

__device__ __forceinline__ float gate(float x, float w, float b) {
    float z = fmaf(x, w, b);
    float s = __frcp_rn(1.0f + __expf(-z));   // sigmoid
    return s * x;
}

__global__ __launch_bounds__(256) void gate3_kernel(
    const float* __restrict__ x1,   // (B,4)  flat
    const v2f*  __restrict__ x2,    // (B,8)  flat, as float2
    const v4f*  __restrict__ x3,    // (B,16) flat, as float4
    const float* __restrict__ Wp,
    const float* __restrict__ bp,
    v4f* __restrict__ out,          // (B,16) flat, as float4
    int nquads)                     // B*4
{
    const float w = Wp[0];
    const float b = bp[0];

    const int stride = gridDim.x * blockDim.x;
    for (int i = blockIdx.x * blockDim.x + threadIdx.x; i < nquads; i += stride) {
        float a  = __builtin_nontemporal_load(&x1[i]);
        v2f  b2  = __builtin_nontemporal_load(&x2[i]);
        v4f  c4  = __builtin_nontemporal_load(&x3[i]);

        float ga  = gate(a, w, b);
        float gb0 = gate(b2.x, w, b);
        float gb1 = gate(b2.y, w, b);

        v4f o;
        o.x = ga + gb0 + gate(c4.x, w, b);
        o.y = ga + gb0 + gate(c4.y, w, b);
        o.z = ga + gb1 + gate(c4.z, w, b);
        o.w = ga + gb1 + gate(c4.w, w, b);

        __builtin_nontemporal_store(o, &out[i]);
    }
}

extern "C" void kernel_launch(void* const* d_in, const int* in_sizes, int n_in,
                              void* d_out, int out_size, void* d_ws, size_t ws_size,
                              hipStream_t stream) {
    const float* x1 = (const float*)d_in[0];
    const v2f*   x2 = (const v2f*)d_in[1];
    const v4f*   x3 = (const v4f*)d_in[2];
    const float* W  = (const float*)d_in[3];
    const float* b  = (const float*)d_in[4];
    v4f* out = (v4f*)d_out;

    int nquads = in_sizes[0];             // B*4 = 8388608
    int block  = 256;
    int grid   = 2048;                    // 256 CUs x 8 blocks, grid-stride x16

    gate3_kernel<<<grid, block, 0, stream>>>(x1, x2, x3, W, b, out, nquads);
}